// Round 1
// baseline (263.767 us; speedup 1.0000x reference)
//
#include <hip/hip_runtime.h>
#include <hip/hip_bf16.h>
#include <stdint.h>

// Problem constants: T=2048, B=1, D=1000, H=1000, L=4.
// N = T*B = 2048 rows. Per layer: gates[2048,4000] = [x|h][2048,2048bf16] @ Wcat[l]^T.
// K layout: x in [0,1000), zeros [1000,1024), h in [1024,2024), zeros [2024,2048).

typedef unsigned short ushort_t;
typedef __bf16 bf16x8 __attribute__((ext_vector_type(8)));
typedef float f32x4 __attribute__((ext_vector_type(4)));
typedef unsigned short ushort8 __attribute__((ext_vector_type(8)));
typedef float float4v __attribute__((ext_vector_type(4)));

#define NROWS 2048
#define KPAD  2048
#define NG    4000
#define HDIM  1000
#define BM 128
#define BN 128
#define BK 32

#define GLOBAL_AS __attribute__((address_space(1)))
#define LDS_AS    __attribute__((address_space(3)))

__device__ __forceinline__ ushort_t f2bf(float f) {
  union { float f; uint32_t u; } x; x.f = f;
  uint32_t u = x.u;
  return (ushort_t)((u + 0x7FFFu + ((u >> 16) & 1u)) >> 16);  // RNE
}

__device__ __forceinline__ float sigf(float v)   { return 1.f / (1.f + __expf(-v)); }
__device__ __forceinline__ float tanhft(float v) { return 2.f / (1.f + __expf(-2.f * v)) - 1.f; }

// ---- fp32 -> bf16 weight concat: Wcat[l][j][0..999]=wih, [1024..2023]=whh, pads zero
__global__ __launch_bounds__(256) void convert_w_kernel(
    const float* __restrict__ wih, const float* __restrict__ whh,
    ushort_t* __restrict__ W) {
  const int l = blockIdx.z;
  const int j = blockIdx.y;
  const int k0 = threadIdx.x * 8;            // 256 threads x 8 = 2048 cols
  const size_t rowIdx = (size_t)l * NG + j;
  ushort8 out = {0,0,0,0,0,0,0,0};
  const float* src = nullptr;
  if (k0 < 1000)                        src = wih + rowIdx * 1000 + k0;         // 1000 % 8 == 0
  else if (k0 >= 1024 && k0 < 2024)     src = whh + rowIdx * 1000 + (k0 - 1024);
  if (src) {
    float4v v0 = *(const float4v*)(src);
    float4v v1 = *(const float4v*)(src + 4);
    out[0]=f2bf(v0[0]); out[1]=f2bf(v0[1]); out[2]=f2bf(v0[2]); out[3]=f2bf(v0[3]);
    out[4]=f2bf(v1[0]); out[5]=f2bf(v1[1]); out[6]=f2bf(v1[2]); out[7]=f2bf(v1[3]);
  }
  *(ushort8*)&W[(rowIdx << 11) + k0] = out;
}

// ---- A[n][k]: bf16(x) in [0,1000), zeros elsewhere (h half rewritten per layer)
__global__ __launch_bounds__(256) void convert_x_kernel(
    const float* __restrict__ x, ushort_t* __restrict__ A) {
  const int n = blockIdx.y;
  const int k0 = threadIdx.x * 8;
  ushort8 out = {0,0,0,0,0,0,0,0};
  if (k0 < 1000) {
    const float* src = x + (size_t)n * 1000 + k0;
    float4v v0 = *(const float4v*)(src);
    float4v v1 = *(const float4v*)(src + 4);
    out[0]=f2bf(v0[0]); out[1]=f2bf(v0[1]); out[2]=f2bf(v0[2]); out[3]=f2bf(v0[3]);
    out[4]=f2bf(v1[0]); out[5]=f2bf(v1[1]); out[6]=f2bf(v1[2]); out[7]=f2bf(v1[3]);
  }
  *(ushort8*)&A[((size_t)n << 11) + k0] = out;
}

// ---- bf16 GEMM (B^T form): gates[2048][4000] = A[2048][2048] * W[4000][2048]^T
// 128x128 tile, BK=32, 4 waves, 16x16x32 MFMA, global_load_lds w=16 staging.
__global__ __launch_bounds__(256) void gemm_kernel(
    const ushort_t* __restrict__ Abuf,
    const ushort_t* __restrict__ Wbuf,   // layer slice [4000][2048]
    float* __restrict__ gates,
    int kend) {
  __shared__ __align__(16) ushort_t As[BM * BK];
  __shared__ __align__(16) ushort_t Bs[BN * BK];
  const int tid  = threadIdx.x;
  const int wave = tid >> 6;
  const int lane = tid & 63;
  const int rowBase = blockIdx.y * BM;
  const int colBase = blockIdx.x * BN;
  const int wr = wave >> 1, wc = wave & 1;     // 2x2 wave grid, 64x64 each
  const int rl = lane & 15, kq = lane >> 4;

  f32x4 acc[4][4] = {};

  for (int k0 = 0; k0 < kend; k0 += BK) {
    // stage A tile: 8192 B via 8 wave-calls (4 waves x 2 rounds), lane = +16B
    #pragma unroll
    for (int r = 0; r < 2; ++r) {
      const int be  = (r * 4 + wave) * 512;      // ushort base in tile
      const int e   = be + lane * 8;
      const int row = e >> 5;                    // 32 bf16 per tile row
      const int kk  = e & 31;
      const ushort_t* g = Abuf + (size_t)(rowBase + row) * KPAD + k0 + kk;
      __builtin_amdgcn_global_load_lds((GLOBAL_AS void*)g,
                                       (LDS_AS void*)&As[be], 16, 0, 0);
    }
    // stage B tile (clamp source row to 3999 for the partial last col-tile)
    #pragma unroll
    for (int r = 0; r < 2; ++r) {
      const int be  = (r * 4 + wave) * 512;
      const int e   = be + lane * 8;
      int row = colBase + (e >> 5);
      if (row > NG - 1) row = NG - 1;
      const int kk  = e & 31;
      const ushort_t* g = Wbuf + (size_t)row * KPAD + k0 + kk;
      __builtin_amdgcn_global_load_lds((GLOBAL_AS void*)g,
                                       (LDS_AS void*)&Bs[be], 16, 0, 0);
    }
    __syncthreads();

    bf16x8 af[4], bfr[4];
    #pragma unroll
    for (int i = 0; i < 4; ++i)
      af[i] = *(const bf16x8*)&As[(wr * 64 + i * 16 + rl) * BK + kq * 8];
    #pragma unroll
    for (int i = 0; i < 4; ++i)
      bfr[i] = *(const bf16x8*)&Bs[(wc * 64 + i * 16 + rl) * BK + kq * 8];

    #pragma unroll
    for (int mi = 0; mi < 4; ++mi)
      #pragma unroll
      for (int ni = 0; ni < 4; ++ni)
        acc[mi][ni] = __builtin_amdgcn_mfma_f32_16x16x32_bf16(
            af[mi], bfr[ni], acc[mi][ni], 0, 0, 0);

    __syncthreads();
  }

  // epilogue: C/D layout col = lane&15, row = (lane>>4)*4 + reg
  #pragma unroll
  for (int mi = 0; mi < 4; ++mi) {
    #pragma unroll
    for (int ni = 0; ni < 4; ++ni) {
      const int col = colBase + wc * 64 + ni * 16 + rl;
      if (col < NG) {
        const int row0 = rowBase + wr * 64 + mi * 16 + kq * 4;
        #pragma unroll
        for (int q = 0; q < 4; ++q)
          gates[(size_t)(row0 + q) * NG + col] = acc[mi][ni][q];
      }
    }
  }
}

// ---- LSTM cell elementwise: gates + bias -> (c,h); h -> bf16 into A[:,1024+j]
__global__ __launch_bounds__(256) void lstm_ew_kernel(
    const float* __restrict__ gates,
    const float* __restrict__ bih,   // pre-offset to layer
    const float* __restrict__ bhh,
    float* __restrict__ c,
    ushort_t* __restrict__ A,
    float* __restrict__ out,
    int layer) {
  const int j = blockIdx.x * 256 + threadIdx.x;
  if (j >= HDIM) return;
  const int n = blockIdx.y;
  const size_t gbase = (size_t)n * NG;
  const float ig = gates[gbase + j]          + bih[j]          + bhh[j];
  const float fg = gates[gbase + 1000 + j]   + bih[1000 + j]   + bhh[1000 + j];
  const float gg = gates[gbase + 2000 + j]   + bih[2000 + j]   + bhh[2000 + j];
  const float og = gates[gbase + 3000 + j]   + bih[3000 + j]   + bhh[3000 + j];
  const float cp = (layer == 0) ? 0.f : c[(size_t)n * HDIM + j];
  const float cn = sigf(fg) * cp + sigf(ig) * tanhft(gg);
  const float hn = sigf(og) * tanhft(cn);
  c[(size_t)n * HDIM + j] = cn;
  A[((size_t)n << 11) + 1024 + j] = f2bf(hn);
  if (layer == 3) out[(size_t)n * HDIM + j] = fmaxf(hn, 0.f);
}

extern "C" void kernel_launch(void* const* d_in, const int* in_sizes, int n_in,
                              void* d_out, int out_size, void* d_ws, size_t ws_size,
                              hipStream_t stream) {
  const float* x   = (const float*)d_in[0];
  const float* wih = (const float*)d_in[1];
  const float* whh = (const float*)d_in[2];
  const float* bih = (const float*)d_in[3];
  const float* bhh = (const float*)d_in[4];
  float* out = (float*)d_out;

  // workspace layout (bytes):
  //   A    bf16 [2048][2048]        @ 0          (8,388,608)
  //   Wcat bf16 [4][4000][2048]     @ 8,388,608  (65,536,000)
  //   gates f32 [2048][4000]        @ 73,924,608 (32,768,000)
  //   c     f32 [2048][1000]        @ 106,692,608 (8,192,000)   total ~114.9 MB
  char* ws = (char*)d_ws;
  ushort_t* A     = (ushort_t*)ws;
  ushort_t* W     = (ushort_t*)(ws + 8388608ull);
  float*    gates = (float*)(ws + 73924608ull);
  float*    c     = (float*)(ws + 106692608ull);

  convert_w_kernel<<<dim3(1, 4000, 4), 256, 0, stream>>>(wih, whh, W);
  convert_x_kernel<<<dim3(1, 2048, 1), 256, 0, stream>>>(x, A);

  for (int l = 0; l < 4; ++l) {
    const int kend = (l == 0) ? 1024 : 2048;   // layer 0: h == 0, skip second K half
    gemm_kernel<<<dim3(32, 16), 256, 0, stream>>>(
        A, W + (size_t)l * NG * KPAD, gates, kend);
    lstm_ew_kernel<<<dim3(4, 2048), 256, 0, stream>>>(
        gates, bih + l * NG, bhh + l * NG, c, A, out, l);
  }
}

// Round 2
// 238.377 us; speedup vs baseline: 1.1065x; 1.1065x over previous
//
#include <hip/hip_runtime.h>
#include <hip/hip_bf16.h>
#include <hip/hip_fp16.h>
#include <stdint.h>

// T=2048, B=1, D=1000, H=1000, L=4. N = T*B = 2048 rows.
// Per layer: gates[2048,4000] = [x|h][2048,2048 bf16] @ Wcat[l]^T.
// K layout: x in [0,1000), zeros [1000,1024), h in [1024,2024), zeros [2024,2048).

typedef unsigned short ushort_t;
typedef __bf16 bf16x8 __attribute__((ext_vector_type(8)));
typedef float f32x4 __attribute__((ext_vector_type(4)));
typedef unsigned short ushort8 __attribute__((ext_vector_type(8)));
typedef float float4v __attribute__((ext_vector_type(4)));

#define NROWS 2048
#define KPAD  2048
#define NG    4000
#define HDIM  1000
#define BM 128
#define BN 128
#define BK 32

#define GLOBAL_AS __attribute__((address_space(1)))
#define LDS_AS    __attribute__((address_space(3)))

__device__ __forceinline__ ushort_t f2bf(float f) {
  union { float f; uint32_t u; } x; x.f = f;
  uint32_t u = x.u;
  return (ushort_t)((u + 0x7FFFu + ((u >> 16) & 1u)) >> 16);  // RNE
}

__device__ __forceinline__ float sigf(float v)   { return 1.f / (1.f + __expf(-v)); }
__device__ __forceinline__ float tanhft(float v) { return 2.f / (1.f + __expf(-2.f * v)) - 1.f; }

// ---- fp32 -> bf16 weight concat: Wcat[l][j][0..999]=wih, [1024..2023]=whh, pads zero
__global__ __launch_bounds__(256) void convert_w_kernel(
    const float* __restrict__ wih, const float* __restrict__ whh,
    ushort_t* __restrict__ W) {
  const int l = blockIdx.z;
  const int j = blockIdx.y;
  const int k0 = threadIdx.x * 8;            // 256 threads x 8 = 2048 cols
  const size_t rowIdx = (size_t)l * NG + j;
  ushort8 out = {0,0,0,0,0,0,0,0};
  const float* src = nullptr;
  if (k0 < 1000)                        src = wih + rowIdx * 1000 + k0;
  else if (k0 >= 1024 && k0 < 2024)     src = whh + rowIdx * 1000 + (k0 - 1024);
  if (src) {
    float4v v0 = *(const float4v*)(src);
    float4v v1 = *(const float4v*)(src + 4);
    out[0]=f2bf(v0[0]); out[1]=f2bf(v0[1]); out[2]=f2bf(v0[2]); out[3]=f2bf(v0[3]);
    out[4]=f2bf(v1[0]); out[5]=f2bf(v1[1]); out[6]=f2bf(v1[2]); out[7]=f2bf(v1[3]);
  }
  *(ushort8*)&W[(rowIdx << 11) + k0] = out;
}

// ---- A[n][k]: bf16(x) in [0,1000), zeros elsewhere (h half rewritten per layer)
__global__ __launch_bounds__(256) void convert_x_kernel(
    const float* __restrict__ x, ushort_t* __restrict__ A) {
  const int n = blockIdx.y;
  const int k0 = threadIdx.x * 8;
  ushort8 out = {0,0,0,0,0,0,0,0};
  if (k0 < 1000) {
    const float* src = x + (size_t)n * 1000 + k0;
    float4v v0 = *(const float4v*)(src);
    float4v v1 = *(const float4v*)(src + 4);
    out[0]=f2bf(v0[0]); out[1]=f2bf(v0[1]); out[2]=f2bf(v0[2]); out[3]=f2bf(v0[3]);
    out[4]=f2bf(v1[0]); out[5]=f2bf(v1[1]); out[6]=f2bf(v1[2]); out[7]=f2bf(v1[3]);
  }
  *(ushort8*)&A[((size_t)n << 11) + k0] = out;
}

// ---- bf16 GEMM (B^T): gates[2048][4000] = A[2048][2048] * W[4000][2048]^T
// 128x128 tile, BK=32, 4 waves, 16x16x32 MFMA, triple-buffered LDS,
// 2-deep global_load_lds prefetch with counted vmcnt (never 0 in main loop).
__global__ __launch_bounds__(256, 2) void gemm_kernel(
    const ushort_t* __restrict__ Abuf,
    const ushort_t* __restrict__ Wbuf,   // layer slice [4000][2048]
    __half* __restrict__ gates,
    int kend) {
  __shared__ __align__(16) ushort_t As[3][BM * BK];
  __shared__ __align__(16) ushort_t Bs[3][BN * BK];
  const int tid  = threadIdx.x;
  const int wave = tid >> 6;
  const int lane = tid & 63;
  const int rowBase = blockIdx.y * BM;
  const int colBase = blockIdx.x * BN;
  const int wr = wave >> 1, wc = wave & 1;     // 2x2 wave grid, 64x64 each
  const int rl = lane & 15, kq = lane >> 4;
  const int NT = kend >> 5;                    // K-steps of 32

  f32x4 acc[4][4] = {};

  // stage one 128x32 A tile + 128x32 B tile into buffer `buf` for K-offset k0.
  // Per wave: 2 A-calls + 2 B-calls = 4 global_load_lds (vmcnt ops) per tile.
  auto stage = [&](int buf, int k0) {
    #pragma unroll
    for (int r = 0; r < 2; ++r) {
      const int be  = (r * 4 + wave) * 512;    // ushort base in tile
      const int e   = be + lane * 8;
      const int row = e >> 5;                  // 32 bf16 per tile row
      const int kk  = e & 31;
      const ushort_t* g = Abuf + (size_t)(rowBase + row) * KPAD + k0 + kk;
      __builtin_amdgcn_global_load_lds((GLOBAL_AS void*)g,
                                       (LDS_AS void*)&As[buf][be], 16, 0, 0);
    }
    #pragma unroll
    for (int r = 0; r < 2; ++r) {
      const int be  = (r * 4 + wave) * 512;
      const int e   = be + lane * 8;
      int row = colBase + (e >> 5);
      if (row > NG - 1) row = NG - 1;          // clamp partial last col-tile
      const int kk  = e & 31;
      const ushort_t* g = Wbuf + (size_t)row * KPAD + k0 + kk;
      __builtin_amdgcn_global_load_lds((GLOBAL_AS void*)g,
                                       (LDS_AS void*)&Bs[buf][be], 16, 0, 0);
    }
  };

  // prologue: 2 tiles in flight
  stage(0, 0);
  stage(1, BK);

  int cur = 0;
  for (int t = 0; t < NT; ++t) {
    if (t + 2 < NT) {
      int nb = cur + 2; if (nb >= 3) nb -= 3;
      stage(nb, (t + 2) * BK);                 // overwrites buffer read at t-1 (safe: post-read barrier at t-1)
      asm volatile("s_waitcnt vmcnt(8)" ::: "memory");   // tile t's 4 loads done; t+1,t+2 in flight
    } else if (t + 2 == NT) {
      asm volatile("s_waitcnt vmcnt(4)" ::: "memory");
    } else {
      asm volatile("s_waitcnt vmcnt(0)" ::: "memory");
    }
    __builtin_amdgcn_s_barrier();              // all waves' tile-t stages visible
    __builtin_amdgcn_sched_barrier(0);

    bf16x8 af[4], bfr[4];
    #pragma unroll
    for (int i = 0; i < 4; ++i)
      af[i] = *(const bf16x8*)&As[cur][(wr * 64 + i * 16 + rl) * BK + kq * 8];
    #pragma unroll
    for (int i = 0; i < 4; ++i)
      bfr[i] = *(const bf16x8*)&Bs[cur][(wc * 64 + i * 16 + rl) * BK + kq * 8];

    asm volatile("s_waitcnt lgkmcnt(0)" ::: "memory");
    __builtin_amdgcn_sched_barrier(0);         // rule 18: keep MFMA below the wait
    __builtin_amdgcn_s_barrier();              // reads done -> next iter may overwrite this buffer

    __builtin_amdgcn_s_setprio(1);
    #pragma unroll
    for (int mi = 0; mi < 4; ++mi)
      #pragma unroll
      for (int ni = 0; ni < 4; ++ni)
        acc[mi][ni] = __builtin_amdgcn_mfma_f32_16x16x32_bf16(
            af[mi], bfr[ni], acc[mi][ni], 0, 0, 0);
    __builtin_amdgcn_s_setprio(0);

    cur = cur + 1; if (cur >= 3) cur = 0;
  }

  // epilogue: C/D layout col = lane&15, row = (lane>>4)*4 + reg ; store fp16
  #pragma unroll
  for (int mi = 0; mi < 4; ++mi) {
    #pragma unroll
    for (int ni = 0; ni < 4; ++ni) {
      const int col = colBase + wc * 64 + ni * 16 + rl;
      if (col < NG) {
        const int row0 = rowBase + wr * 64 + mi * 16 + kq * 4;
        #pragma unroll
        for (int q = 0; q < 4; ++q)
          gates[(size_t)(row0 + q) * NG + col] = __float2half(acc[mi][ni][q]);
      }
    }
  }
}

// ---- LSTM cell elementwise: gates + bias -> (c,h); h -> bf16 into A[:,1024+j]
__global__ __launch_bounds__(256) void lstm_ew_kernel(
    const __half* __restrict__ gates,
    const float* __restrict__ bih,   // pre-offset to layer
    const float* __restrict__ bhh,
    float* __restrict__ c,
    ushort_t* __restrict__ A,
    float* __restrict__ out,
    int layer) {
  const int j = blockIdx.x * 256 + threadIdx.x;
  if (j >= HDIM) return;
  const int n = blockIdx.y;
  const size_t gbase = (size_t)n * NG;
  const float ig = __half2float(gates[gbase + j])        + bih[j]        + bhh[j];
  const float fg = __half2float(gates[gbase + 1000 + j]) + bih[1000 + j] + bhh[1000 + j];
  const float gg = __half2float(gates[gbase + 2000 + j]) + bih[2000 + j] + bhh[2000 + j];
  const float og = __half2float(gates[gbase + 3000 + j]) + bih[3000 + j] + bhh[3000 + j];
  const float cp = (layer == 0) ? 0.f : c[(size_t)n * HDIM + j];
  const float cn = sigf(fg) * cp + sigf(ig) * tanhft(gg);
  const float hn = sigf(og) * tanhft(cn);
  c[(size_t)n * HDIM + j] = cn;
  A[((size_t)n << 11) + 1024 + j] = f2bf(hn);
  if (layer == 3) out[(size_t)n * HDIM + j] = fmaxf(hn, 0.f);
}

extern "C" void kernel_launch(void* const* d_in, const int* in_sizes, int n_in,
                              void* d_out, int out_size, void* d_ws, size_t ws_size,
                              hipStream_t stream) {
  const float* x   = (const float*)d_in[0];
  const float* wih = (const float*)d_in[1];
  const float* whh = (const float*)d_in[2];
  const float* bih = (const float*)d_in[3];
  const float* bhh = (const float*)d_in[4];
  float* out = (float*)d_out;

  // workspace layout (bytes):
  //   A     bf16 [2048][2048]     @ 0            (8,388,608)
  //   Wcat  bf16 [4][4000][2048]  @ 8,388,608    (65,536,000)
  //   gates f16  [2048][4000]     @ 73,924,608   (16,384,000)
  //   c     f32  [2048][1000]     @ 90,308,608   (8,192,000)   total ~98.5 MB
  char* ws = (char*)d_ws;
  ushort_t* A     = (ushort_t*)ws;
  ushort_t* W     = (ushort_t*)(ws + 8388608ull);
  __half*   gates = (__half*)(ws + 73924608ull);
  float*    c     = (float*)(ws + 90308608ull);

  convert_w_kernel<<<dim3(1, 4000, 4), 256, 0, stream>>>(wih, whh, W);
  convert_x_kernel<<<dim3(1, 2048, 1), 256, 0, stream>>>(x, A);

  for (int l = 0; l < 4; ++l) {
    const int kend = (l == 0) ? 1024 : 2048;   // layer 0: h == 0, skip second K half
    gemm_kernel<<<dim3(32, 16), 256, 0, stream>>>(
        A, W + (size_t)l * NG * KPAD, gates, kend);
    lstm_ew_kernel<<<dim3(4, 2048), 256, 0, stream>>>(
        gates, bih + l * NG, bhh + l * NG, c, A, out, l);
  }
}

// Round 3
// 206.262 us; speedup vs baseline: 1.2788x; 1.1557x over previous
//
#include <hip/hip_runtime.h>
#include <hip/hip_bf16.h>
#include <stdint.h>

// T=2048, B=1, D=1000, H=1000, L=4. N = 2048 rows.
// Per layer: gates[2048, 4096pad] = [x|h] @ Wcat[l]^T, gate cols interleaved
// col = 4*j + g (g in {i,f,g,o}), then LSTM cell fused in the GEMM epilogue.
// K layout: x in [0,1000)+pad -> Xb[2048][1024]; h in Hb ping-pong [2048][1024].
// W k-cols: [0,1000)=wih, [1024,2024)=whh, rest zero.

typedef unsigned short ushort_t;
typedef __bf16 bf16x8 __attribute__((ext_vector_type(8)));
typedef float f32x4 __attribute__((ext_vector_type(4)));
typedef unsigned short ushort8 __attribute__((ext_vector_type(8)));
typedef float float4v __attribute__((ext_vector_type(4)));

#define XK    1024
#define KPAD  2048
#define NG2   4096
#define HDIM  1000
#define BM 128
#define BN 128
#define BK 32

#define GLOBAL_AS __attribute__((address_space(1)))
#define LDS_AS    __attribute__((address_space(3)))

__device__ __forceinline__ ushort_t f2bf(float f) {
  union { float f; uint32_t u; } x; x.f = f;
  uint32_t u = x.u;
  return (ushort_t)((u + 0x7FFFu + ((u >> 16) & 1u)) >> 16);  // RNE
}

__device__ __forceinline__ float sigf(float v)   { return 1.f / (1.f + __expf(-v)); }
__device__ __forceinline__ float tanhft(float v) { return 2.f / (1.f + __expf(-2.f * v)) - 1.f; }

// ---- W concat+interleave: Wcat[l][c][k], c=4j+g <- source row g*1000+j.
// k: [0,1000) wih, [1024,2024) whh, else 0. Rows c with j>=1000 are zero.
__global__ __launch_bounds__(256) void convert_w_kernel(
    const float* __restrict__ wih, const float* __restrict__ whh,
    ushort_t* __restrict__ W) {
  const int l = blockIdx.z;
  const int c = blockIdx.y;                  // 0..4095
  const int j = c >> 2, g = c & 3;
  const int k0 = threadIdx.x * 8;
  ushort8 out = {0,0,0,0,0,0,0,0};
  if (j < HDIM) {
    const size_t srow = (size_t)l * 4000 + g * 1000 + j;
    const float* src = nullptr;
    if (k0 < 1000)                        src = wih + srow * 1000 + k0;
    else if (k0 >= 1024 && k0 < 2024)     src = whh + srow * 1000 + (k0 - 1024);
    if (src) {
      float4v v0 = *(const float4v*)(src);
      float4v v1 = *(const float4v*)(src + 4);
      out[0]=f2bf(v0[0]); out[1]=f2bf(v0[1]); out[2]=f2bf(v0[2]); out[3]=f2bf(v0[3]);
      out[4]=f2bf(v1[0]); out[5]=f2bf(v1[1]); out[6]=f2bf(v1[2]); out[7]=f2bf(v1[3]);
    }
  }
  *(ushort8*)&W[((size_t)l * NG2 + c) * KPAD + k0] = out;
}

// ---- x -> bf16 Xb[2048][1024] (cols 1000..1023 zero)
__global__ __launch_bounds__(256) void convert_x_kernel(
    const float* __restrict__ x, ushort_t* __restrict__ Xb) {
  const int n  = blockIdx.y * 2 + (threadIdx.x >> 7);
  const int k0 = (threadIdx.x & 127) * 8;
  ushort8 out = {0,0,0,0,0,0,0,0};
  if (k0 < 1000) {
    const float* src = x + (size_t)n * 1000 + k0;
    float4v v0 = *(const float4v*)(src);
    float4v v1 = *(const float4v*)(src + 4);
    out[0]=f2bf(v0[0]); out[1]=f2bf(v0[1]); out[2]=f2bf(v0[2]); out[3]=f2bf(v0[3]);
    out[4]=f2bf(v1[0]); out[5]=f2bf(v1[1]); out[6]=f2bf(v1[2]); out[7]=f2bf(v1[3]);
  }
  *(ushort8*)&Xb[((size_t)n << 10) + k0] = out;
}

// ---- bsum[l][c] = bih+bhh in interleaved order (j>=1000 -> 0)
__global__ __launch_bounds__(256) void bias_kernel(
    const float* __restrict__ bih, const float* __restrict__ bhh,
    float* __restrict__ bsum) {
  const int l = blockIdx.y;
  const int c = blockIdx.x * 256 + threadIdx.x;   // 0..4095
  const int j = c >> 2, g = c & 3;
  float v = 0.f;
  if (j < HDIM) {
    const int r = l * 4000 + g * 1000 + j;
    v = bih[r] + bhh[r];
  }
  bsum[(size_t)l * NG2 + c] = v;
}

// ---- fused GEMM + LSTM cell.
// 128x128 tile, 4 waves, 16x16x32 MFMA, 3-buffer LDS, 2-deep prefetch,
// counted vmcnt; XOR-swizzled LDS K-slots (pre-swizzled global source).
__global__ __launch_bounds__(256, 2) void gemm_kernel(
    const ushort_t* __restrict__ Xb,
    const ushort_t* __restrict__ Hin,
    const ushort_t* __restrict__ Wl,     // layer slice [4096][2048]
    const float* __restrict__ bsum,      // layer slice [4096]
    float* __restrict__ cbuf,
    ushort_t* __restrict__ Hout,
    float* __restrict__ out,
    int layer, int kend) {
  __shared__ __align__(16) char smem[49152];
  ushort_t (*As)[BM * BK] = (ushort_t (*)[BM * BK])smem;            // 3 x 8 KB
  ushort_t (*Bs)[BN * BK] = (ushort_t (*)[BN * BK])(smem + 24576);  // 3 x 8 KB
  float* ex = (float*)smem;                                         // 64x132 f32 (33 KB)

  const int tid  = threadIdx.x;
  const int wave = tid >> 6;
  const int lane = tid & 63;
  const int rowBase = blockIdx.y * BM;
  const int colBase = blockIdx.x * BN;
  const int wr = wave >> 1, wc = wave & 1;     // 2x2 wave grid, 64x64 each
  const int rl = lane & 15, kq = lane >> 4;
  const int NT = kend >> 5;

  f32x4 acc[4][4] = {};

  // stage A(128x32)+B(128x32) into buffer `buf`; 4 global_load_lds per wave.
  // LDS dest linear (lane*16B); global source K-slot pre-swizzled by
  // slot ^= (row>>1)&3 (permutation within each 64B row -> coalescing kept).
  auto stage = [&](int buf, int k0) {
    const ushort_t* asrc = (k0 < XK) ? (Xb + k0) : (Hin + (k0 - XK));
    #pragma unroll
    for (int r = 0; r < 2; ++r) {
      const int be  = (r * 4 + wave) * 512;        // ushort base, 1 KB-aligned
      const int row = (be >> 5) + (lane >> 2);     // tile row of this lane's 16B
      const int sl  = (lane & 3) ^ ((row >> 1) & 3);
      const ushort_t* g = asrc + (size_t)(rowBase + row) * XK + sl * 8;
      __builtin_amdgcn_global_load_lds((GLOBAL_AS void*)g,
                                       (LDS_AS void*)&As[buf][be], 16, 0, 0);
    }
    #pragma unroll
    for (int r = 0; r < 2; ++r) {
      const int be  = (r * 4 + wave) * 512;
      const int row = (be >> 5) + (lane >> 2);
      const int sl  = (lane & 3) ^ ((row >> 1) & 3);
      const ushort_t* g = Wl + (size_t)(colBase + row) * KPAD + k0 + sl * 8;
      __builtin_amdgcn_global_load_lds((GLOBAL_AS void*)g,
                                       (LDS_AS void*)&Bs[buf][be], 16, 0, 0);
    }
  };

  stage(0, 0);
  stage(1, BK);

  int cur = 0;
  for (int t = 0; t < NT; ++t) {
    if (t + 2 < NT) {
      int nb = cur + 2; if (nb >= 3) nb -= 3;
      stage(nb, (t + 2) * BK);
      asm volatile("s_waitcnt vmcnt(8)" ::: "memory");   // tile t ready; t+1,t+2 in flight
    } else if (t + 2 == NT) {
      asm volatile("s_waitcnt vmcnt(4)" ::: "memory");
    } else {
      asm volatile("s_waitcnt vmcnt(0)" ::: "memory");
    }
    __builtin_amdgcn_s_barrier();
    __builtin_amdgcn_sched_barrier(0);

    bf16x8 af[4], bfr[4];
    #pragma unroll
    for (int i = 0; i < 4; ++i) {
      const int ar = wr * 64 + i * 16 + rl;
      af[i] = *(const bf16x8*)&As[cur][ar * BK + ((kq ^ ((ar >> 1) & 3)) * 8)];
    }
    #pragma unroll
    for (int i = 0; i < 4; ++i) {
      const int br = wc * 64 + i * 16 + rl;
      bfr[i] = *(const bf16x8*)&Bs[cur][br * BK + ((kq ^ ((br >> 1) & 3)) * 8)];
    }

    asm volatile("s_waitcnt lgkmcnt(0)" ::: "memory");
    __builtin_amdgcn_sched_barrier(0);
    __builtin_amdgcn_s_barrier();        // reads done -> staging may overwrite

    __builtin_amdgcn_s_setprio(1);
    #pragma unroll
    for (int mi = 0; mi < 4; ++mi)
      #pragma unroll
      for (int ni = 0; ni < 4; ++ni)
        acc[mi][ni] = __builtin_amdgcn_mfma_f32_16x16x32_bf16(
            af[mi], bfr[ni], acc[mi][ni], 0, 0, 0);
    __builtin_amdgcn_s_setprio(0);

    cur = cur + 1; if (cur >= 3) cur = 0;
  }

  // ---- fused epilogue: exchange acc through LDS, compute LSTM cell.
  // Block covers j = jTile..jTile+31 (col = 4j+g). Two half-tiles of 64 rows.
  const int jTile = blockIdx.x * 32;
  #pragma unroll
  for (int h = 0; h < 2; ++h) {
    __syncthreads();
    if (wr == h) {                       // waves owning rows h*64..h*64+63
      #pragma unroll
      for (int mi = 0; mi < 4; ++mi) {
        const int lr = mi * 16 + kq * 4;
        #pragma unroll
        for (int ni = 0; ni < 4; ++ni) {
          const int lc = wc * 64 + ni * 16 + rl;
          #pragma unroll
          for (int q = 0; q < 4; ++q)
            ex[(lr + q) * 132 + lc] = acc[mi][ni][q];
        }
      }
    }
    __syncthreads();
    #pragma unroll
    for (int p = 0; p < 8; ++p) {
      const int idx = p * 256 + tid;     // 0..2047
      const int lr  = idx >> 5;          // 0..63
      const int j   = idx & 31;
      const int jg  = jTile + j;
      if (jg < HDIM) {
        const int n = rowBase + h * 64 + lr;
        float4v gv = *(const float4v*)&ex[lr * 132 + 4 * j];
        float4v bv = *(const float4v*)&bsum[(size_t)(jTile + j) * 4];
        const float ig = gv[0] + bv[0];
        const float fg = gv[1] + bv[1];
        const float gg = gv[2] + bv[2];
        const float og = gv[3] + bv[3];
        const float cp = (layer == 0) ? 0.f : cbuf[(size_t)n * HDIM + jg];
        const float cn = sigf(fg) * cp + sigf(ig) * tanhft(gg);
        const float hn = sigf(og) * tanhft(cn);
        cbuf[(size_t)n * HDIM + jg] = cn;
        Hout[((size_t)n << 10) + jg] = f2bf(hn);
        if (layer == 3) out[(size_t)n * HDIM + jg] = fmaxf(hn, 0.f);
      }
    }
  }
}

extern "C" void kernel_launch(void* const* d_in, const int* in_sizes, int n_in,
                              void* d_out, int out_size, void* d_ws, size_t ws_size,
                              hipStream_t stream) {
  const float* x   = (const float*)d_in[0];
  const float* wih = (const float*)d_in[1];
  const float* whh = (const float*)d_in[2];
  const float* bih = (const float*)d_in[3];
  const float* bhh = (const float*)d_in[4];
  float* out = (float*)d_out;

  // workspace (bytes):
  //   Xb   bf16 [2048][1024]      @ 0           (4,194,304)
  //   Hb   bf16 2x[2048][1024]    @ 4,194,304   (8,388,608)
  //   Wcat bf16 [4][4096][2048]   @ 12,582,912  (67,108,864)
  //   bsum f32  [4][4096]         @ 79,691,776  (65,536)
  //   cbuf f32  [2048][1000]      @ 79,757,312  (8,192,000)   total ~88 MB
  char* ws = (char*)d_ws;
  ushort_t* Xb   = (ushort_t*)ws;
  ushort_t* Hb   = (ushort_t*)(ws + 4194304ull);
  ushort_t* W    = (ushort_t*)(ws + 12582912ull);
  float*    bsum = (float*)(ws + 79691776ull);
  float*    cbuf = (float*)(ws + 79757312ull);
  const size_t NH = 2048ull * 1024ull;   // elements per H buffer

  convert_w_kernel<<<dim3(1, 4096, 4), 256, 0, stream>>>(wih, whh, W);
  convert_x_kernel<<<dim3(1, 1024), 256, 0, stream>>>(x, Xb);
  bias_kernel<<<dim3(16, 4), 256, 0, stream>>>(bih, bhh, bsum);

  for (int l = 0; l < 4; ++l) {
    const int kend = (l == 0) ? 1024 : 2048;     // layer 0: h == 0
    const ushort_t* Hin  = Hb + (size_t)(l & 1) * NH;
    ushort_t*       Hout = Hb + (size_t)((l + 1) & 1) * NH;
    gemm_kernel<<<dim3(32, 16), 256, 0, stream>>>(
        Xb, Hin, W + (size_t)l * NG2 * KPAD, bsum + (size_t)l * NG2,
        cbuf, Hout, out, l, kend);
  }
}